// Round 17
// baseline (48.910 us; speedup 1.0000x reference)
//
#include <hip/hip_runtime.h>
#include <math.h>

typedef __attribute__((ext_vector_type(8))) short bf16x8;
typedef __attribute__((ext_vector_type(8))) unsigned short u16x8;
typedef __attribute__((ext_vector_type(4))) float f32x4;
typedef __attribute__((ext_vector_type(4))) unsigned int u32x4;

#define B_ 4
#define L_ 2048
#define S_ 2048
#define H_ 8
#define E_ 64
#define D_ 64
#define NT_ 32
#define TILE_BYTES 16384
#define IMG_BYTES ((size_t)B_ * H_ * NT_ * TILE_BYTES)            // 16 MB tile images
#define PSZ ((size_t)B_ * L_ * H_ * D_ * 2)                        // 8 MB bf16 partial
#define PK_OFF(k) (IMG_BYTES + (size_t)((k) - 1) * PSZ)            // k = 1..3
#define LARR_OFF(c) (IMG_BYTES + 3 * PSZ + (size_t)(c) * (B_ * H_ * L_ * 4))
#define WS_NEEDED  IMG_BYTES
#define WS2_NEEDED (IMG_BYTES + 3 * PSZ + 4 * (size_t)(B_ * H_ * L_ * 4))
#define SCL (0.125f * 1.44269504088896f)   // 1/sqrt(E) * log2(e)

__device__ __forceinline__ unsigned short f2bf(float x) {
    unsigned int u = __builtin_bit_cast(unsigned int, x);
    u += 0x7fffu + ((u >> 16) & 1u);
    return (unsigned short)(u >> 16);
}
// kv-row permute so S^T C-fragment layout == PV A-operand layout (verified rounds 1-16)
__device__ __forceinline__ int rho(int r) {
    return (r & 32) | (((r >> 2) & 1) << 4) | (((r >> 3) & 3) << 2) | (r & 3);
}
__device__ __forceinline__ void gload16(const void* g, void* l) {
    __builtin_amdgcn_global_load_lds((const __attribute__((address_space(1))) unsigned int*)g,
                                     (__attribute__((address_space(3))) unsigned int*)l, 16, 0, 0);
}

// ---------------- prep: K -> bf16 tile image, V -> V^T image; XCD-aligned to consumer ----------------
__global__ __launch_bounds__(256) void prep_kv(const float* __restrict__ K,
                                               const float* __restrict__ V,
                                               unsigned short* __restrict__ ws)
{
    __shared__ __align__(16) unsigned short vt[64][80];
    const int tid = threadIdx.x;
    const int bid = blockIdx.x;
    const int kt  = bid >> 5;
    const int bh  = (((bid >> 3) & 3) << 3) | (bid & 7);      // bid%8 == bh%8
    const int b   = bh >> 3, h = bh & 7;
    const int s0  = kt * 64;
    const int r   = tid >> 2;
    const int e0  = (tid & 3) * 16;

    const float* krow = K + (((size_t)(b * S_ + s0 + r)) * H_ + h) * E_ + e0;
    const float* vrow = V + (((size_t)(b * S_ + s0 + r)) * H_ + h) * D_ + e0;
    char* tile = (char*)(ws) + ((size_t)(bh * NT_ + kt) * TILE_BYTES);

    unsigned short kb[16];
    #pragma unroll
    for (int i = 0; i < 4; ++i) {
        f32x4 k4 = *(const f32x4*)(krow + i * 4);
        #pragma unroll
        for (int jq = 0; jq < 4; ++jq) kb[i * 4 + jq] = f2bf(k4[jq]);
    }
    {
        const int rr = rho(r);
        const int m  = (rr & 7) << 4;
        char* kbase = tile + rr * 128;
        u32x4 lo, hi;
        #pragma unroll
        for (int jq = 0; jq < 4; ++jq) {
            lo[jq] = (unsigned)kb[2 * jq] | ((unsigned)kb[2 * jq + 1] << 16);
            hi[jq] = (unsigned)kb[8 + 2 * jq] | ((unsigned)kb[9 + 2 * jq] << 16);
        }
        *(u32x4*)(kbase + ((2 * e0) ^ m))      = lo;
        *(u32x4*)(kbase + ((2 * e0 + 16) ^ m)) = hi;
    }
    #pragma unroll
    for (int i = 0; i < 4; ++i) {
        f32x4 v4 = *(const f32x4*)(vrow + i * 4);
        #pragma unroll
        for (int jq = 0; jq < 4; ++jq) vt[e0 + i * 4 + jq][r] = f2bf(v4[jq]);
    }
    __syncthreads();
    {
        const int d  = tid >> 2;
        const int c0 = (tid & 3) * 16;
        const int m  = (d & 7) << 4;
        char* vbase = tile + 8192 + d * 128;
        u32x4 lo = *(const u32x4*)&vt[d][c0];
        u32x4 hi = *(const u32x4*)&vt[d][c0 + 8];
        *(u32x4*)(vbase + ((2 * c0) ^ m))      = lo;
        *(u32x4*)(vbase + ((2 * c0 + 16) ^ m)) = hi;
    }
}

// ---- attn19: 1280 short blocks (<=8 iters), 4 waves/128-row group, kv-chunk split-K ----
// desc-by-length (jj, chunk) table: lengths 8...8 (28), then 6,4,2 (4 each)
__device__ __constant__ const signed char JJ_TAB[40] = {
    15,15,15,15, 14,14,14, 13,13,13, 12,12,12, 11,11,11, 10,10, 9,9, 8,8, 7,7, 6, 5, 4, 3,
    14,10,6,2,  13,9,5,1,  12,8,4,0 };
__device__ __constant__ const signed char CC_TAB[40] = {
    0,1,2,3, 0,1,2, 0,1,2, 0,1,2, 0,1,2, 0,1, 0,1, 0,1, 0,1, 0, 0, 0, 0,
    3,2,1,0, 3,2,1,0, 3,2,1,0 };

__global__ __launch_bounds__(256, 4) void attn19(const float* __restrict__ Q,
                                                 const unsigned short* __restrict__ ws,
                                                 float* __restrict__ O,
                                                 char* __restrict__ wsc)
{
    __shared__ __align__(16) char pool[2 * 16384];   // 32 KB dbuf

    const int tid  = threadIdx.x;
    const int lane = tid & 63;
    const int w    = tid >> 6;        // wave 0..3, rows jj*128 + w*32
    const int lq   = lane & 15;
    const int gl   = lane >> 4;

    const int bid = blockIdx.x;
    const int bh  = bid & 31;                     // XCD bh%8 == prep's XCD
    const int idx = bid >> 5;                     // 0..39, desc length
    const int jj  = JJ_TAB[idx];
    const int cch = CC_TAB[idx];
    const int b0  = bh >> 3, h = bh & 7;

    const int nt  = 2 * jj + 2;
    const int nch = (jj >> 2) + 1;                // chunks for this group
    const int kb  = cch * 8;
    int ke = kb + 8; if (ke > nt) ke = nt;
    const int cw  = 2 * jj + (w >> 1);            // wave's diagonal tile
    const int q0  = jj * 128 + w * 32;
    int qrow[2];
    qrow[0] = q0 + lq;
    qrow[1] = q0 + 16 + lq;

    // Q fragments (B-operand), scale*log2e folded => scores in exp2 domain
    bf16x8 qf[2][2];
    #pragma unroll
    for (int qs = 0; qs < 2; ++qs) {
        const float* qptr = Q + (((size_t)(b0 * L_ + qrow[qs])) * H_ + h) * E_;
        #pragma unroll
        for (int eb = 0; eb < 2; ++eb) {
            const float* pq = qptr + eb * 32 + gl * 8;
            f32x4 a = *(const f32x4*)pq;
            f32x4 b = *(const f32x4*)(pq + 4);
            bf16x8 qv;
            #pragma unroll
            for (int k = 0; k < 4; ++k) {
                qv[k]     = (short)f2bf(a[k] * SCL);
                qv[4 + k] = (short)f2bf(b[k] * SCL);
            }
            qf[qs][eb] = qv;
        }
    }

    f32x4 acc[2][4] = {};
    float ls[2] = {0.f, 0.f};

    const char* tb = (const char*)ws + (size_t)bh * NT_ * TILE_BYTES;

    #define STAGE19(T, BUF) do { \
        const char* gp_ = tb + (size_t)(T) * TILE_BYTES + tid * 16; \
        char* lp_ = pool + (BUF) * 16384 + tid * 16; \
        gload16(gp_, lp_);                 gload16(gp_ + 4096, lp_ + 4096); \
        gload16(gp_ + 8192, lp_ + 8192);   gload16(gp_ + 12288, lp_ + 12288); \
    } while (0)

    STAGE19(kb, 0);
    int cur = 0;
    for (int kt = kb; kt < ke; ++kt) {
        if (kt + 1 < ke) {
            STAGE19(kt + 1, cur ^ 1);
            asm volatile("s_waitcnt vmcnt(4)" ::: "memory");
        } else {
            asm volatile("s_waitcnt vmcnt(0)" ::: "memory");
        }
        __builtin_amdgcn_s_barrier();
        __builtin_amdgcn_sched_barrier(0);

        if (kt <= cw) {
            const char* Kl = pool + cur * 16384;
            const char* Vl = Kl + 8192;
            const int kv0 = kt * 64;
            const bool maskit = (kt == cw);

            u32x4 pw[2][2];
            #pragma unroll
            for (int st = 0; st < 4; ++st) {
                const int row = st * 16 + lq;
                const int mm = (row & 7) << 4;
                const char* kr = Kl + row * 128;
                bf16x8 k0 = *(const bf16x8*)(kr + ((16 * gl) ^ mm));
                bf16x8 k1 = *(const bf16x8*)(kr + ((64 + 16 * gl) ^ mm));
                #pragma unroll
                for (int qs = 0; qs < 2; ++qs) {
                    f32x4 z = {0.f, 0.f, 0.f, 0.f};
                    __builtin_amdgcn_s_setprio(1);
                    f32x4 cc = __builtin_amdgcn_mfma_f32_16x16x32_bf16(k0, qf[qs][0], z, 0, 0, 0);
                    cc = __builtin_amdgcn_mfma_f32_16x16x32_bf16(k1, qf[qs][1], cc, 0, 0, 0);
                    __builtin_amdgcn_s_setprio(0);
                    if (maskit) {
                        #pragma unroll
                        for (int r = 0; r < 4; ++r) {
                            const int kv = kv0 + 32 * (st >> 1) + 8 * gl + 4 * (st & 1) + r;
                            if (kv > qrow[qs]) cc[r] = -INFINITY;
                        }
                    }
                    f32x4 ev;
                    #pragma unroll
                    for (int r = 0; r < 4; ++r)
                        asm("v_exp_f32 %0, %1" : "=v"(ev[r]) : "v"(cc[r]));
                    ls[qs] += (ev[0] + ev[1]) + (ev[2] + ev[3]);
                    asm("v_cvt_pk_bf16_f32 %0, %1, %2" : "=v"(pw[qs][st >> 1][2 * (st & 1)])     : "v"(ev[0]), "v"(ev[1]));
                    asm("v_cvt_pk_bf16_f32 %0, %1, %2" : "=v"(pw[qs][st >> 1][2 * (st & 1) + 1]) : "v"(ev[2]), "v"(ev[3]));
                }
            }

            #pragma unroll
            for (int dt = 0; dt < 4; ++dt) {
                const int row = dt * 16 + lq;
                const int mm = (row & 7) << 4;
                bf16x8 v0 = *(const bf16x8*)(Vl + row * 128 + ((16 * gl) ^ mm));
                bf16x8 v1 = *(const bf16x8*)(Vl + row * 128 + ((64 + 16 * gl) ^ mm));
                __builtin_amdgcn_s_setprio(1);
                #pragma unroll
                for (int qs = 0; qs < 2; ++qs) {
                    acc[qs][dt] = __builtin_amdgcn_mfma_f32_16x16x32_bf16(v0, __builtin_bit_cast(bf16x8, pw[qs][0]), acc[qs][dt], 0, 0, 0);
                    acc[qs][dt] = __builtin_amdgcn_mfma_f32_16x16x32_bf16(v1, __builtin_bit_cast(bf16x8, pw[qs][1]), acc[qs][dt], 0, 0, 0);
                }
                __builtin_amdgcn_s_setprio(0);
            }
        }
        __builtin_amdgcn_s_barrier();
        cur ^= 1;
    }
    #undef STAGE19

    // epilogue
    #pragma unroll
    for (int qs = 0; qs < 2; ++qs) {
        float l = ls[qs] + __shfl_xor(ls[qs], 16);
        l += __shfl_xor(l, 32);
        const size_t obase = (((size_t)(b0 * L_ + qrow[qs])) * H_ + h) * D_;
        if (nch == 1) {
            const float inv = 1.0f / l;
            float* op = O + obase;
            #pragma unroll
            for (int dt = 0; dt < 4; ++dt) {
                f32x4 o;
                #pragma unroll
                for (int r = 0; r < 4; ++r) o[r] = acc[qs][dt][r] * inv;
                *(f32x4*)(op + dt * 16 + 4 * gl) = o;
            }
        } else {
            float* lc = (float*)(wsc + LARR_OFF(cch));
            if (lane < 16) lc[(b0 * H_ + h) * L_ + qrow[qs]] = l;
            if (cch == 0) {
                float* op = O + obase;
                #pragma unroll
                for (int dt = 0; dt < 4; ++dt)
                    *(f32x4*)(op + dt * 16 + 4 * gl) = acc[qs][dt];
            } else {
                unsigned short* pp = (unsigned short*)(wsc + PK_OFF(cch)) + obase;
                #pragma unroll
                for (int dt = 0; dt < 4; ++dt) {
                    unsigned int w0, w1;
                    asm("v_cvt_pk_bf16_f32 %0, %1, %2" : "=v"(w0) : "v"(acc[qs][dt][0]), "v"(acc[qs][dt][1]));
                    asm("v_cvt_pk_bf16_f32 %0, %1, %2" : "=v"(w1) : "v"(acc[qs][dt][2]), "v"(acc[qs][dt][3]));
                    *(uint2*)(pp + dt * 16 + 4 * gl) = make_uint2(w0, w1);
                }
            }
        }
    }
}

// ---------------- combine: rows with nch>=2 only; O = (P0 + sum Pk)/(sum lk) ----------------
__global__ __launch_bounds__(256) void combine19(float* __restrict__ O,
                                                 const char* __restrict__ wsc)
{
    const int f = (blockIdx.x * 256 + threadIdx.x) * 8;
    const int l = (f >> 9) & (L_ - 1);
    const int jj = l >> 7;
    if (jj < 4) return;                          // single-chunk rows already final
    const int nch = (jj >> 2) + 1;               // 2..4
    const int h = (f >> 6) & 7;
    const int b = f >> 20;
    const int li = (b * 8 + h) * L_ + l;

    float lt = ((const float*)(wsc + LARR_OFF(0)))[li]
             + ((const float*)(wsc + LARR_OFF(1)))[li];
    f32x4 a0 = *(f32x4*)(O + f);
    f32x4 a1 = *(f32x4*)(O + f + 4);
    #pragma unroll
    for (int k = 1; k <= 3; ++k) {
        if (k >= nch) break;
        u16x8 pb = *(const u16x8*)((const unsigned short*)(wsc + PK_OFF(k)) + f);
        #pragma unroll
        for (int r = 0; r < 4; ++r) {
            a0[r] += __builtin_bit_cast(float, (unsigned)pb[r] << 16);
            a1[r] += __builtin_bit_cast(float, (unsigned)pb[4 + r] << 16);
        }
        if (k >= 2) lt += ((const float*)(wsc + LARR_OFF(k)))[li];
    }
    const float inv = 1.0f / lt;
    #pragma unroll
    for (int r = 0; r < 4; ++r) { a0[r] *= inv; a1[r] *= inv; }
    *(f32x4*)(O + f)     = a0;
    *(f32x4*)(O + f + 4) = a1;
}

// ---------------- fallback (round-1 kernel, proven) for tiny ws ----------------
#define KPITCH 72
__global__ __launch_bounds__(256, 2) void attn_fwd_fb(
    const float* __restrict__ Q, const float* __restrict__ K,
    const float* __restrict__ V, float* __restrict__ O)
{
    __shared__ unsigned short Klds[64 * KPITCH];
    __shared__ unsigned short Vlds[64 * KPITCH];
    const int tid = threadIdx.x, lane = tid & 63, w = tid >> 6;
    const int lq = lane & 15, g = lane >> 4;
    const int bid = blockIdx.x, qb = bid & 31, bh = bid >> 5;
    const int b0 = bh >> 3, h = bh & 7;
    const int q0 = qb * 64, qrow = q0 + w * 16 + lq;
    const float* qptr = Q + ((size_t)(b0 * L_ + qrow) * H_ + h) * E_;
    bf16x8 qf[2];
    #pragma unroll
    for (int eb = 0; eb < 2; ++eb) {
        const float* pp = qptr + eb * 32 + g * 8;
        f32x4 a = *(const f32x4*)pp; f32x4 b = *(const f32x4*)(pp + 4);
        bf16x8 qv;
        #pragma unroll
        for (int jq = 0; jq < 4; ++jq) { qv[jq] = (short)f2bf(a[jq] * 0.125f); qv[4 + jq] = (short)f2bf(b[jq] * 0.125f); }
        qf[eb] = qv;
    }
    const int tr = tid >> 2, tc = tid & 3;
    const int rh = rho(tr);
    f32x4 acc[4] = {};
    float mrow = -INFINITY, lrow = 0.f;
    for (int kt = 0; kt < qb + 1; ++kt) {
        const int kv0 = kt * 64;
        __syncthreads();
        {
            const float* krow = K + ((size_t)((b0 * S_ + kv0 + tr)) * H_ + h) * E_;
            const float* vrow = V + ((size_t)((b0 * S_ + kv0 + tr)) * H_ + h) * D_;
            #pragma unroll
            for (int i = 0; i < 4; ++i) {
                const int e0 = tc * 4 + i * 16;
                f32x4 k4 = *(const f32x4*)(krow + e0);
                unsigned int lo = (unsigned)f2bf(k4[0]) | ((unsigned)f2bf(k4[1]) << 16);
                unsigned int hi = (unsigned)f2bf(k4[2]) | ((unsigned)f2bf(k4[3]) << 16);
                *(uint2*)&Klds[rh * KPITCH + e0] = make_uint2(lo, hi);
                f32x4 v4 = *(const f32x4*)(vrow + e0);
                #pragma unroll
                for (int k2 = 0; k2 < 4; ++k2) Vlds[(e0 + k2) * KPITCH + tr] = f2bf(v4[k2]);
            }
        }
        __syncthreads();
        f32x4 sc[4];
        #pragma unroll
        for (int st = 0; st < 4; ++st) {
            const unsigned short* kr = &Klds[(st * 16 + lq) * KPITCH];
            bf16x8 ka0 = *(const bf16x8*)(kr + 8 * g);
            bf16x8 ka1 = *(const bf16x8*)(kr + 32 + 8 * g);
            f32x4 cc = {0.f, 0.f, 0.f, 0.f};
            cc = __builtin_amdgcn_mfma_f32_16x16x32_bf16(ka0, qf[0], cc, 0, 0, 0);
            cc = __builtin_amdgcn_mfma_f32_16x16x32_bf16(ka1, qf[1], cc, 0, 0, 0);
            sc[st] = cc;
        }
        float tmax = -INFINITY;
        #pragma unroll
        for (int st = 0; st < 4; ++st) {
            const int kvb = kv0 + 32 * (st >> 1) + 8 * g + 4 * (st & 1);
            #pragma unroll
            for (int r = 0; r < 4; ++r) { if (kvb + r > qrow) sc[st][r] = -INFINITY; tmax = fmaxf(tmax, sc[st][r]); }
        }
        tmax = fmaxf(tmax, __shfl_xor(tmax, 16));
        tmax = fmaxf(tmax, __shfl_xor(tmax, 32));
        const float mnew = fmaxf(mrow, tmax);
        const float corr = __expf(mrow - mnew);
        float pv[4][4]; float tsum = 0.f;
        #pragma unroll
        for (int st = 0; st < 4; ++st)
            #pragma unroll
            for (int r = 0; r < 4; ++r) { float e = __expf(sc[st][r] - mnew); pv[st][r] = e; tsum += e; }
        tsum += __shfl_xor(tsum, 16); tsum += __shfl_xor(tsum, 32);
        lrow = lrow * corr + tsum; mrow = mnew;
        #pragma unroll
        for (int dt = 0; dt < 4; ++dt)
            #pragma unroll
            for (int r = 0; r < 4; ++r) acc[dt][r] *= corr;
        bf16x8 pb[2];
        #pragma unroll
        for (int bb = 0; bb < 2; ++bb)
            #pragma unroll
            for (int s = 0; s < 2; ++s)
                #pragma unroll
                for (int r = 0; r < 4; ++r) pb[bb][4 * s + r] = (short)f2bf(pv[2 * bb + s][r]);
        #pragma unroll
        for (int bb = 0; bb < 2; ++bb)
            #pragma unroll
            for (int dt = 0; dt < 4; ++dt) {
                bf16x8 va = *(const bf16x8*)&Vlds[(dt * 16 + lq) * KPITCH + 32 * bb + 8 * g];
                acc[dt] = __builtin_amdgcn_mfma_f32_16x16x32_bf16(va, pb[bb], acc[dt], 0, 0, 0);
            }
    }
    const float inv = 1.0f / lrow;
    float* optr = O + ((size_t)(b0 * L_ + qrow) * H_ + h) * D_;
    #pragma unroll
    for (int dt = 0; dt < 4; ++dt) {
        f32x4 o;
        #pragma unroll
        for (int r = 0; r < 4; ++r) o[r] = acc[dt][r] * inv;
        *(f32x4*)(optr + dt * 16 + 4 * g) = o;
    }
}

extern "C" void kernel_launch(void* const* d_in, const int* in_sizes, int n_in,
                              void* d_out, int out_size, void* d_ws, size_t ws_size,
                              hipStream_t stream) {
    const float* Q = (const float*)d_in[0];
    const float* K = (const float*)d_in[1];
    const float* V = (const float*)d_in[2];
    float* O = (float*)d_out;
    if (ws_size >= WS2_NEEDED) {
        prep_kv<<<dim3(B_ * H_ * NT_), 256, 0, stream>>>(K, V, (unsigned short*)d_ws);
        attn19<<<dim3(1280), 256, 0, stream>>>(Q, (const unsigned short*)d_ws, O, (char*)d_ws);
        combine19<<<dim3(2048), 256, 0, stream>>>(O, (const char*)d_ws);
    } else {
        attn_fwd_fb<<<dim3(B_ * H_ * 32), 256, 0, stream>>>(Q, K, V, O);
    }
}

// Round 18
// 42.626 us; speedup vs baseline: 1.1474x; 1.1474x over previous
//
#include <hip/hip_runtime.h>
#include <math.h>

typedef __attribute__((ext_vector_type(8))) short bf16x8;
typedef __attribute__((ext_vector_type(4))) float f32x4;
typedef __attribute__((ext_vector_type(4))) unsigned int u32x4;

#define B_ 4
#define L_ 2048
#define S_ 2048
#define H_ 8
#define E_ 64
#define D_ 64
#define NT_ 32
#define TILE_BYTES 16384
#define WS_NEEDED ((size_t)B_ * H_ * NT_ * TILE_BYTES)   // 16 MB tile images only
#define SCL (0.125f * 1.44269504088896f)                  // 1/sqrt(E) * log2(e)

__device__ __forceinline__ unsigned short f2bf(float x) {
    unsigned int u = __builtin_bit_cast(unsigned int, x);
    u += 0x7fffu + ((u >> 16) & 1u);
    return (unsigned short)(u >> 16);
}
// kv-row permute so S^T C-fragment layout == PV A-operand layout (verified rounds 1-17)
__device__ __forceinline__ int rho(int r) {
    return (r & 32) | (((r >> 2) & 1) << 4) | (((r >> 3) & 3) << 2) | (r & 3);
}
__device__ __forceinline__ void gload16(const void* g, void* l) {
    __builtin_amdgcn_global_load_lds((const __attribute__((address_space(1))) unsigned int*)g,
                                     (__attribute__((address_space(3))) unsigned int*)l, 16, 0, 0);
}

// ---------------- prep: K -> bf16 tile image, V -> V^T image; XCD-aligned to consumer ----------------
__global__ __launch_bounds__(256) void prep_kv(const float* __restrict__ K,
                                               const float* __restrict__ V,
                                               unsigned short* __restrict__ ws)
{
    __shared__ __align__(16) unsigned short vt[64][80];
    const int tid = threadIdx.x;
    const int bid = blockIdx.x;
    const int kt  = bid >> 5;
    const int bh  = (((bid >> 3) & 3) << 3) | (bid & 7);      // bid%8 == bh%8
    const int b   = bh >> 3, h = bh & 7;
    const int s0  = kt * 64;
    const int r   = tid >> 2;
    const int e0  = (tid & 3) * 16;

    const float* krow = K + (((size_t)(b * S_ + s0 + r)) * H_ + h) * E_ + e0;
    const float* vrow = V + (((size_t)(b * S_ + s0 + r)) * H_ + h) * D_ + e0;
    char* tile = (char*)(ws) + ((size_t)(bh * NT_ + kt) * TILE_BYTES);

    unsigned short kb[16];
    #pragma unroll
    for (int i = 0; i < 4; ++i) {
        f32x4 k4 = *(const f32x4*)(krow + i * 4);
        #pragma unroll
        for (int jq = 0; jq < 4; ++jq) kb[i * 4 + jq] = f2bf(k4[jq]);
    }
    {
        const int rr = rho(r);
        const int m  = (rr & 7) << 4;
        char* kbase = tile + rr * 128;
        u32x4 lo, hi;
        #pragma unroll
        for (int jq = 0; jq < 4; ++jq) {
            lo[jq] = (unsigned)kb[2 * jq] | ((unsigned)kb[2 * jq + 1] << 16);
            hi[jq] = (unsigned)kb[8 + 2 * jq] | ((unsigned)kb[9 + 2 * jq] << 16);
        }
        *(u32x4*)(kbase + ((2 * e0) ^ m))      = lo;
        *(u32x4*)(kbase + ((2 * e0 + 16) ^ m)) = hi;
    }
    #pragma unroll
    for (int i = 0; i < 4; ++i) {
        f32x4 v4 = *(const f32x4*)(vrow + i * 4);
        #pragma unroll
        for (int jq = 0; jq < 4; ++jq) vt[e0 + i * 4 + jq][r] = f2bf(v4[jq]);
    }
    __syncthreads();
    {
        const int d  = tid >> 2;
        const int c0 = (tid & 3) * 16;
        const int m  = (d & 7) << 4;
        char* vbase = tile + 8192 + d * 128;
        u32x4 lo = *(const u32x4*)&vt[d][c0];
        u32x4 hi = *(const u32x4*)&vt[d][c0 + 8];
        *(u32x4*)(vbase + ((2 * c0) ^ m))      = lo;
        *(u32x4*)(vbase + ((2 * c0 + 16) ^ m)) = hi;
    }
}

// ---- attn11: split-K inside the block (2 teams x 4 waves, equal chunks), LDS combine ----
// (round-11 proven 41.9us build; only change: setprio pairs removed — T5 null/negative in lockstep, m190)
#define STAGE2(I, BUF) do { \
    const char* sa = tb + (size_t)(I) * TILE_BYTES; \
    const char* sb = tb + (size_t)(jj + 1 + (I)) * TILE_BYTES; \
    char* da = pool + (BUF) * 16384 + tid * 16; \
    char* db = pool + 32768 + (BUF) * 16384 + tid * 16; \
    gload16(sa + tid * 16, da); \
    gload16(sa + 8192 + tid * 16, da + 8192); \
    gload16(sb + tid * 16, db); \
    gload16(sb + 8192 + tid * 16, db + 8192); \
} while (0)

__global__ __launch_bounds__(512, 4) void attn11(const float* __restrict__ Q,
                                                 const unsigned short* __restrict__ ws,
                                                 float* __restrict__ O)
{
    __shared__ __align__(16) char pool[65536];   // 2 teams x 2 bufs x 16KB; aliased for combine

    const int tid  = threadIdx.x;
    const int lane = tid & 63;
    const int w    = tid >> 6;        // wave 0..7
    const int team = w >> 2;          // 0 = kv [0, jj+1), 1 = kv [jj+1, 2jj+2)
    const int tw   = w & 3;           // wave within team; both teams cover the same rows
    const int lq   = lane & 15;
    const int g    = lane >> 4;

    const int bid = blockIdx.x;
    const int bh  = bid & 31;                     // XCD bh%8 == prep's XCD
    const int q   = bid >> 5;                     // 0..15
    const int jj  = (q < 8) ? (15 - q) : (q - 8); // desc-then-asc: CU pair sums = const
    const int b0  = bh >> 3, h = bh & 7;

    const int q0 = jj * 128 + tw * 32;
    int qrow[2];
    qrow[0] = q0 + lq;
    qrow[1] = q0 + 16 + lq;
    const int dktB = 2 * jj + (tw >> 1);          // team-B wave active iff kt <= dktB

    // Q fragments (B-operand), scale*log2e folded => scores in exp2 domain
    bf16x8 qf[2][2];
    #pragma unroll
    for (int qs = 0; qs < 2; ++qs) {
        const float* qptr = Q + (((size_t)(b0 * L_ + qrow[qs])) * H_ + h) * E_;
        #pragma unroll
        for (int eb = 0; eb < 2; ++eb) {
            const float* pq = qptr + eb * 32 + g * 8;
            f32x4 a = *(const f32x4*)pq;
            f32x4 b = *(const f32x4*)(pq + 4);
            bf16x8 qv;
            #pragma unroll
            for (int k = 0; k < 4; ++k) {
                qv[k]     = (short)f2bf(a[k] * SCL);
                qv[4 + k] = (short)f2bf(b[k] * SCL);
            }
            qf[qs][eb] = qv;
        }
    }

    f32x4 acc[2][4] = {};
    float ls[2] = {0.f, 0.f};

    const char* tb = (const char*)ws + (size_t)bh * NT_ * TILE_BYTES;

    STAGE2(0, 0);     // both teams' first tiles

    int cur = 0;
    for (int i = 0; i <= jj; ++i) {
        if (i < jj) {
            STAGE2(i + 1, cur ^ 1);
            asm volatile("s_waitcnt vmcnt(4)" ::: "memory");
        } else {
            asm volatile("s_waitcnt vmcnt(0)" ::: "memory");
        }
        __builtin_amdgcn_s_barrier();
        __builtin_amdgcn_sched_barrier(0);

        const int kt = team ? (jj + 1 + i) : i;
        const bool active = (team == 0) || (kt <= dktB);
        if (active) {
            const char* Kl = pool + team * 32768 + cur * 16384;
            const char* Vl = Kl + 8192;
            const int kv0 = kt * 64;
            const bool maskit = (kt >= 2 * jj);   // diagonal can only be in the last 2 tiles

            u32x4 pw[2][2];
            #pragma unroll
            for (int st = 0; st < 4; ++st) {
                const int row = st * 16 + lq;
                const int mm = (row & 7) << 4;
                const char* kr = Kl + row * 128;
                bf16x8 k0 = *(const bf16x8*)(kr + ((16 * g) ^ mm));
                bf16x8 k1 = *(const bf16x8*)(kr + ((64 + 16 * g) ^ mm));
                #pragma unroll
                for (int qs = 0; qs < 2; ++qs) {
                    f32x4 z = {0.f, 0.f, 0.f, 0.f};
                    f32x4 cc = __builtin_amdgcn_mfma_f32_16x16x32_bf16(k0, qf[qs][0], z, 0, 0, 0);
                    cc = __builtin_amdgcn_mfma_f32_16x16x32_bf16(k1, qf[qs][1], cc, 0, 0, 0);
                    if (maskit) {
                        #pragma unroll
                        for (int r = 0; r < 4; ++r) {
                            const int kv = kv0 + 32 * (st >> 1) + 8 * g + 4 * (st & 1) + r;
                            if (kv > qrow[qs]) cc[r] = -INFINITY;
                        }
                    }
                    f32x4 ev;
                    #pragma unroll
                    for (int r = 0; r < 4; ++r)
                        asm("v_exp_f32 %0, %1" : "=v"(ev[r]) : "v"(cc[r]));
                    ls[qs] += (ev[0] + ev[1]) + (ev[2] + ev[3]);
                    asm("v_cvt_pk_bf16_f32 %0, %1, %2" : "=v"(pw[qs][st >> 1][2 * (st & 1)])     : "v"(ev[0]), "v"(ev[1]));
                    asm("v_cvt_pk_bf16_f32 %0, %1, %2" : "=v"(pw[qs][st >> 1][2 * (st & 1) + 1]) : "v"(ev[2]), "v"(ev[3]));
                }
            }

            #pragma unroll
            for (int dt = 0; dt < 4; ++dt) {
                const int row = dt * 16 + lq;
                const int mm = (row & 7) << 4;
                bf16x8 v0 = *(const bf16x8*)(Vl + row * 128 + ((16 * g) ^ mm));
                bf16x8 v1 = *(const bf16x8*)(Vl + row * 128 + ((64 + 16 * g) ^ mm));
                #pragma unroll
                for (int qs = 0; qs < 2; ++qs) {
                    acc[qs][dt] = __builtin_amdgcn_mfma_f32_16x16x32_bf16(v0, __builtin_bit_cast(bf16x8, pw[qs][0]), acc[qs][dt], 0, 0, 0);
                    acc[qs][dt] = __builtin_amdgcn_mfma_f32_16x16x32_bf16(v1, __builtin_bit_cast(bf16x8, pw[qs][1]), acc[qs][dt], 0, 0, 0);
                }
            }
        }

        __builtin_amdgcn_s_barrier();
        cur ^= 1;
    }

    // ---- in-block combine: team B -> LDS, team A adds + normalizes + stores ----
    __builtin_amdgcn_s_barrier();                 // all tile reads done; alias pool as float
    float* sacc = (float*)pool;                   // [128][68] (+4 pad)
    float* sls  = (float*)(pool + 128 * 68 * 4);  // [128]
    if (team == 1) {
        #pragma unroll
        for (int qs = 0; qs < 2; ++qs) {
            const int rowl = 32 * tw + 16 * qs + lq;
            float l = ls[qs] + __shfl_xor(ls[qs], 16);
            l += __shfl_xor(l, 32);
            if (g == 0) sls[rowl] = l;
            #pragma unroll
            for (int dt = 0; dt < 4; ++dt)
                *(f32x4*)&sacc[rowl * 68 + dt * 16 + 4 * g] = acc[qs][dt];
        }
    }
    __syncthreads();
    if (team == 0) {
        #pragma unroll
        for (int qs = 0; qs < 2; ++qs) {
            const int rowl = 32 * tw + 16 * qs + lq;
            float l = ls[qs] + __shfl_xor(ls[qs], 16);
            l += __shfl_xor(l, 32);
            const float inv = 1.0f / (l + sls[rowl]);
            float* op = O + (((size_t)(b0 * L_ + qrow[qs])) * H_ + h) * D_;
            #pragma unroll
            for (int dt = 0; dt < 4; ++dt) {
                f32x4 p = *(const f32x4*)&sacc[rowl * 68 + dt * 16 + 4 * g];
                f32x4 o;
                #pragma unroll
                for (int r = 0; r < 4; ++r) o[r] = (acc[qs][dt][r] + p[r]) * inv;
                *(f32x4*)(op + dt * 16 + 4 * g) = o;
            }
        }
    }
}

// ---------------- fallback (round-1 kernel, proven) for tiny ws ----------------
#define KPITCH 72
__global__ __launch_bounds__(256, 2) void attn_fwd_fb(
    const float* __restrict__ Q, const float* __restrict__ K,
    const float* __restrict__ V, float* __restrict__ O)
{
    __shared__ unsigned short Klds[64 * KPITCH];
    __shared__ unsigned short Vlds[64 * KPITCH];
    const int tid = threadIdx.x, lane = tid & 63, w = tid >> 6;
    const int lq = lane & 15, g = lane >> 4;
    const int bid = blockIdx.x, qb = bid & 31, bh = bid >> 5;
    const int b0 = bh >> 3, h = bh & 7;
    const int q0 = qb * 64, qrow = q0 + w * 16 + lq;
    const float* qptr = Q + ((size_t)(b0 * L_ + qrow) * H_ + h) * E_;
    bf16x8 qf[2];
    #pragma unroll
    for (int eb = 0; eb < 2; ++eb) {
        const float* pp = qptr + eb * 32 + g * 8;
        f32x4 a = *(const f32x4*)pp; f32x4 b = *(const f32x4*)(pp + 4);
        bf16x8 qv;
        #pragma unroll
        for (int jq = 0; jq < 4; ++jq) { qv[jq] = (short)f2bf(a[jq] * 0.125f); qv[4 + jq] = (short)f2bf(b[jq] * 0.125f); }
        qf[eb] = qv;
    }
    const int tr = tid >> 2, tc = tid & 3;
    const int rh = rho(tr);
    f32x4 acc[4] = {};
    float mrow = -INFINITY, lrow = 0.f;
    for (int kt = 0; kt < qb + 1; ++kt) {
        const int kv0 = kt * 64;
        __syncthreads();
        {
            const float* krow = K + ((size_t)((b0 * S_ + kv0 + tr)) * H_ + h) * E_;
            const float* vrow = V + ((size_t)((b0 * S_ + kv0 + tr)) * H_ + h) * D_;
            #pragma unroll
            for (int i = 0; i < 4; ++i) {
                const int e0 = tc * 4 + i * 16;
                f32x4 k4 = *(const f32x4*)(krow + e0);
                unsigned int lo = (unsigned)f2bf(k4[0]) | ((unsigned)f2bf(k4[1]) << 16);
                unsigned int hi = (unsigned)f2bf(k4[2]) | ((unsigned)f2bf(k4[3]) << 16);
                *(uint2*)&Klds[rh * KPITCH + e0] = make_uint2(lo, hi);
                f32x4 v4 = *(const f32x4*)(vrow + e0);
                #pragma unroll
                for (int k2 = 0; k2 < 4; ++k2) Vlds[(e0 + k2) * KPITCH + tr] = f2bf(v4[k2]);
            }
        }
        __syncthreads();
        f32x4 sc[4];
        #pragma unroll
        for (int st = 0; st < 4; ++st) {
            const unsigned short* kr = &Klds[(st * 16 + lq) * KPITCH];
            bf16x8 ka0 = *(const bf16x8*)(kr + 8 * g);
            bf16x8 ka1 = *(const bf16x8*)(kr + 32 + 8 * g);
            f32x4 cc = {0.f, 0.f, 0.f, 0.f};
            cc = __builtin_amdgcn_mfma_f32_16x16x32_bf16(ka0, qf[0], cc, 0, 0, 0);
            cc = __builtin_amdgcn_mfma_f32_16x16x32_bf16(ka1, qf[1], cc, 0, 0, 0);
            sc[st] = cc;
        }
        float tmax = -INFINITY;
        #pragma unroll
        for (int st = 0; st < 4; ++st) {
            const int kvb = kv0 + 32 * (st >> 1) + 8 * g + 4 * (st & 1);
            #pragma unroll
            for (int r = 0; r < 4; ++r) { if (kvb + r > qrow) sc[st][r] = -INFINITY; tmax = fmaxf(tmax, sc[st][r]); }
        }
        tmax = fmaxf(tmax, __shfl_xor(tmax, 16));
        tmax = fmaxf(tmax, __shfl_xor(tmax, 32));
        const float mnew = fmaxf(mrow, tmax);
        const float corr = __expf(mrow - mnew);
        float pv[4][4]; float tsum = 0.f;
        #pragma unroll
        for (int st = 0; st < 4; ++st)
            #pragma unroll
            for (int r = 0; r < 4; ++r) { float e = __expf(sc[st][r] - mnew); pv[st][r] = e; tsum += e; }
        tsum += __shfl_xor(tsum, 16); tsum += __shfl_xor(tsum, 32);
        lrow = lrow * corr + tsum; mrow = mnew;
        #pragma unroll
        for (int dt = 0; dt < 4; ++dt)
            #pragma unroll
            for (int r = 0; r < 4; ++r) acc[dt][r] *= corr;
        bf16x8 pb[2];
        #pragma unroll
        for (int bb = 0; bb < 2; ++bb)
            #pragma unroll
            for (int s = 0; s < 2; ++s)
                #pragma unroll
                for (int r = 0; r < 4; ++r) pb[bb][4 * s + r] = (short)f2bf(pv[2 * bb + s][r]);
        #pragma unroll
        for (int bb = 0; bb < 2; ++bb)
            #pragma unroll
            for (int dt = 0; dt < 4; ++dt) {
                bf16x8 va = *(const bf16x8*)&Vlds[(dt * 16 + lq) * KPITCH + 32 * bb + 8 * g];
                acc[dt] = __builtin_amdgcn_mfma_f32_16x16x32_bf16(va, pb[bb], acc[dt], 0, 0, 0);
            }
    }
    const float inv = 1.0f / lrow;
    float* optr = O + ((size_t)(b0 * L_ + qrow) * H_ + h) * D_;
    #pragma unroll
    for (int dt = 0; dt < 4; ++dt) {
        f32x4 o;
        #pragma unroll
        for (int r = 0; r < 4; ++r) o[r] = acc[dt][r] * inv;
        *(f32x4*)(optr + dt * 16 + 4 * g) = o;
    }
}

extern "C" void kernel_launch(void* const* d_in, const int* in_sizes, int n_in,
                              void* d_out, int out_size, void* d_ws, size_t ws_size,
                              hipStream_t stream) {
    const float* Q = (const float*)d_in[0];
    const float* K = (const float*)d_in[1];
    const float* V = (const float*)d_in[2];
    float* O = (float*)d_out;
    if (ws_size >= WS_NEEDED) {
        prep_kv<<<dim3(B_ * H_ * NT_), 256, 0, stream>>>(K, V, (unsigned short*)d_ws);
        attn11<<<dim3(512), 512, 0, stream>>>(Q, (const unsigned short*)d_ws, O);
    } else {
        attn_fwd_fb<<<dim3(B_ * H_ * 32), 256, 0, stream>>>(Q, K, V, O);
    }
}

// Round 19
// 41.305 us; speedup vs baseline: 1.1841x; 1.0320x over previous
//
#include <hip/hip_runtime.h>
#include <math.h>

typedef __attribute__((ext_vector_type(8))) short bf16x8;
typedef __attribute__((ext_vector_type(4))) float f32x4;
typedef __attribute__((ext_vector_type(4))) unsigned int u32x4;

#define B_ 4
#define L_ 2048
#define S_ 2048
#define H_ 8
#define E_ 64
#define D_ 64
#define NT_ 32
#define TILE_BYTES 16384
#define WS_NEEDED ((size_t)B_ * H_ * NT_ * TILE_BYTES)   // 16 MB tile images only
#define SCL (0.125f * 1.44269504088896f)                  // 1/sqrt(E) * log2(e)

__device__ __forceinline__ unsigned short f2bf(float x) {
    unsigned int u = __builtin_bit_cast(unsigned int, x);
    u += 0x7fffu + ((u >> 16) & 1u);
    return (unsigned short)(u >> 16);
}
// kv-row permute so S^T C-fragment layout == PV A-operand layout (verified rounds 1-18)
__device__ __forceinline__ int rho(int r) {
    return (r & 32) | (((r >> 2) & 1) << 4) | (((r >> 3) & 3) << 2) | (r & 3);
}
__device__ __forceinline__ void gload16(const void* g, void* l) {
    __builtin_amdgcn_global_load_lds((const __attribute__((address_space(1))) unsigned int*)g,
                                     (__attribute__((address_space(3))) unsigned int*)l, 16, 0, 0);
}

// ---------------- prep: K -> bf16 tile image, V -> V^T image; XCD-aligned to consumer ----------------
__global__ __launch_bounds__(256) void prep_kv(const float* __restrict__ K,
                                               const float* __restrict__ V,
                                               unsigned short* __restrict__ ws)
{
    __shared__ __align__(16) unsigned short vt[64][80];
    const int tid = threadIdx.x;
    const int bid = blockIdx.x;
    const int kt  = bid >> 5;
    const int bh  = (((bid >> 3) & 3) << 3) | (bid & 7);      // bid%8 == bh%8
    const int b   = bh >> 3, h = bh & 7;
    const int s0  = kt * 64;
    const int r   = tid >> 2;
    const int e0  = (tid & 3) * 16;

    const float* krow = K + (((size_t)(b * S_ + s0 + r)) * H_ + h) * E_ + e0;
    const float* vrow = V + (((size_t)(b * S_ + s0 + r)) * H_ + h) * D_ + e0;
    char* tile = (char*)(ws) + ((size_t)(bh * NT_ + kt) * TILE_BYTES);

    unsigned short kb[16];
    #pragma unroll
    for (int i = 0; i < 4; ++i) {
        f32x4 k4 = *(const f32x4*)(krow + i * 4);
        #pragma unroll
        for (int jq = 0; jq < 4; ++jq) kb[i * 4 + jq] = f2bf(k4[jq]);
    }
    {
        const int rr = rho(r);
        const int m  = (rr & 7) << 4;
        char* kbase = tile + rr * 128;
        u32x4 lo, hi;
        #pragma unroll
        for (int jq = 0; jq < 4; ++jq) {
            lo[jq] = (unsigned)kb[2 * jq] | ((unsigned)kb[2 * jq + 1] << 16);
            hi[jq] = (unsigned)kb[8 + 2 * jq] | ((unsigned)kb[9 + 2 * jq] << 16);
        }
        *(u32x4*)(kbase + ((2 * e0) ^ m))      = lo;
        *(u32x4*)(kbase + ((2 * e0 + 16) ^ m)) = hi;
    }
    #pragma unroll
    for (int i = 0; i < 4; ++i) {
        f32x4 v4 = *(const f32x4*)(vrow + i * 4);
        #pragma unroll
        for (int jq = 0; jq < 4; ++jq) vt[e0 + i * 4 + jq][r] = f2bf(v4[jq]);
    }
    __syncthreads();
    {
        const int d  = tid >> 2;
        const int c0 = (tid & 3) * 16;
        const int m  = (d & 7) << 4;
        char* vbase = tile + 8192 + d * 128;
        u32x4 lo = *(const u32x4*)&vt[d][c0];
        u32x4 hi = *(const u32x4*)&vt[d][c0 + 8];
        *(u32x4*)(vbase + ((2 * c0) ^ m))      = lo;
        *(u32x4*)(vbase + ((2 * c0 + 16) ^ m)) = hi;
    }
}

// ---- attn20: attn11 structure with ONE barrier/iter ----
// Per iter i: vmcnt(0) [own tile-i loads] -> BARRIER [all waves' tile-i landed AND
// compute(i-1) done in all waves (program order)] -> STAGE(i+1) into the buffer
// freed by this barrier -> compute(i). 2 buffers/team, 64KB total, 2 blocks/CU.
#define STAGE2(I, BUF) do { \
    const char* sa = tb + (size_t)(I) * TILE_BYTES; \
    const char* sb = tb + (size_t)(jj + 1 + (I)) * TILE_BYTES; \
    char* da = pool + (BUF) * 16384 + tid * 16; \
    char* db = pool + 32768 + (BUF) * 16384 + tid * 16; \
    gload16(sa + tid * 16, da); \
    gload16(sa + 8192 + tid * 16, da + 8192); \
    gload16(sb + tid * 16, db); \
    gload16(sb + 8192 + tid * 16, db + 8192); \
} while (0)

__global__ __launch_bounds__(512, 4) void attn20(const float* __restrict__ Q,
                                                 const unsigned short* __restrict__ ws,
                                                 float* __restrict__ O)
{
    __shared__ __align__(16) char pool[65536];   // 2 teams x 2 bufs x 16KB; aliased for combine

    const int tid  = threadIdx.x;
    const int lane = tid & 63;
    const int w    = tid >> 6;        // wave 0..7
    const int team = w >> 2;          // 0 = kv [0, jj+1), 1 = kv [jj+1, 2jj+2)
    const int tw   = w & 3;           // wave within team; both teams cover the same rows
    const int lq   = lane & 15;
    const int g    = lane >> 4;

    const int bid = blockIdx.x;
    const int bh  = bid & 31;                     // XCD bh%8 == prep's XCD
    const int q   = bid >> 5;                     // 0..15
    const int jj  = (q < 8) ? (15 - q) : (q - 8); // desc-then-asc: CU pair sums = const
    const int b0  = bh >> 3, h = bh & 7;

    const int q0 = jj * 128 + tw * 32;
    int qrow[2];
    qrow[0] = q0 + lq;
    qrow[1] = q0 + 16 + lq;
    const int dktB = 2 * jj + (tw >> 1);          // team-B wave active iff kt <= dktB

    // Q fragments (B-operand), scale*log2e folded => scores in exp2 domain
    bf16x8 qf[2][2];
    #pragma unroll
    for (int qs = 0; qs < 2; ++qs) {
        const float* qptr = Q + (((size_t)(b0 * L_ + qrow[qs])) * H_ + h) * E_;
        #pragma unroll
        for (int eb = 0; eb < 2; ++eb) {
            const float* pq = qptr + eb * 32 + g * 8;
            f32x4 a = *(const f32x4*)pq;
            f32x4 b = *(const f32x4*)(pq + 4);
            bf16x8 qv;
            #pragma unroll
            for (int k = 0; k < 4; ++k) {
                qv[k]     = (short)f2bf(a[k] * SCL);
                qv[4 + k] = (short)f2bf(b[k] * SCL);
            }
            qf[qs][eb] = qv;
        }
    }

    f32x4 acc[2][4] = {};
    float ls[2] = {0.f, 0.f};

    const char* tb = (const char*)ws + (size_t)bh * NT_ * TILE_BYTES;

    STAGE2(0, 0);     // both teams' first tiles

    int cur = 0;
    for (int i = 0; i <= jj; ++i) {
        asm volatile("s_waitcnt vmcnt(0)" ::: "memory");   // own tile-i loads landed
        __builtin_amdgcn_s_barrier();                      // all waves: tile-i in LDS, compute(i-1) done
        __builtin_amdgcn_sched_barrier(0);
        if (i < jj) STAGE2(i + 1, cur ^ 1);                // into buffer freed by the barrier

        const int kt = team ? (jj + 1 + i) : i;
        const bool active = (team == 0) || (kt <= dktB);
        if (active) {
            const char* Kl = pool + team * 32768 + cur * 16384;
            const char* Vl = Kl + 8192;
            const int kv0 = kt * 64;
            const bool maskit = (kt >= 2 * jj);   // diagonal can only be in the last 2 tiles

            u32x4 pw[2][2];
            #pragma unroll
            for (int st = 0; st < 4; ++st) {
                const int row = st * 16 + lq;
                const int mm = (row & 7) << 4;
                const char* kr = Kl + row * 128;
                bf16x8 k0 = *(const bf16x8*)(kr + ((16 * g) ^ mm));
                bf16x8 k1 = *(const bf16x8*)(kr + ((64 + 16 * g) ^ mm));
                #pragma unroll
                for (int qs = 0; qs < 2; ++qs) {
                    f32x4 z = {0.f, 0.f, 0.f, 0.f};
                    f32x4 cc = __builtin_amdgcn_mfma_f32_16x16x32_bf16(k0, qf[qs][0], z, 0, 0, 0);
                    cc = __builtin_amdgcn_mfma_f32_16x16x32_bf16(k1, qf[qs][1], cc, 0, 0, 0);
                    if (maskit) {
                        #pragma unroll
                        for (int r = 0; r < 4; ++r) {
                            const int kv = kv0 + 32 * (st >> 1) + 8 * g + 4 * (st & 1) + r;
                            if (kv > qrow[qs]) cc[r] = -INFINITY;
                        }
                    }
                    f32x4 ev;
                    #pragma unroll
                    for (int r = 0; r < 4; ++r)
                        asm("v_exp_f32 %0, %1" : "=v"(ev[r]) : "v"(cc[r]));
                    ls[qs] += (ev[0] + ev[1]) + (ev[2] + ev[3]);
                    asm("v_cvt_pk_bf16_f32 %0, %1, %2" : "=v"(pw[qs][st >> 1][2 * (st & 1)])     : "v"(ev[0]), "v"(ev[1]));
                    asm("v_cvt_pk_bf16_f32 %0, %1, %2" : "=v"(pw[qs][st >> 1][2 * (st & 1) + 1]) : "v"(ev[2]), "v"(ev[3]));
                }
            }

            #pragma unroll
            for (int dt = 0; dt < 4; ++dt) {
                const int row = dt * 16 + lq;
                const int mm = (row & 7) << 4;
                bf16x8 v0 = *(const bf16x8*)(Vl + row * 128 + ((16 * g) ^ mm));
                bf16x8 v1 = *(const bf16x8*)(Vl + row * 128 + ((64 + 16 * g) ^ mm));
                #pragma unroll
                for (int qs = 0; qs < 2; ++qs) {
                    acc[qs][dt] = __builtin_amdgcn_mfma_f32_16x16x32_bf16(v0, __builtin_bit_cast(bf16x8, pw[qs][0]), acc[qs][dt], 0, 0, 0);
                    acc[qs][dt] = __builtin_amdgcn_mfma_f32_16x16x32_bf16(v1, __builtin_bit_cast(bf16x8, pw[qs][1]), acc[qs][dt], 0, 0, 0);
                }
            }
        }
        cur ^= 1;
    }

    // ---- in-block combine: team B -> LDS, team A adds + normalizes + stores ----
    __builtin_amdgcn_s_barrier();                 // all tile reads done; alias pool as float
    float* sacc = (float*)pool;                   // [128][68] (+4 pad)
    float* sls  = (float*)(pool + 128 * 68 * 4);  // [128]
    if (team == 1) {
        #pragma unroll
        for (int qs = 0; qs < 2; ++qs) {
            const int rowl = 32 * tw + 16 * qs + lq;
            float l = ls[qs] + __shfl_xor(ls[qs], 16);
            l += __shfl_xor(l, 32);
            if (g == 0) sls[rowl] = l;
            #pragma unroll
            for (int dt = 0; dt < 4; ++dt)
                *(f32x4*)&sacc[rowl * 68 + dt * 16 + 4 * g] = acc[qs][dt];
        }
    }
    __syncthreads();
    if (team == 0) {
        #pragma unroll
        for (int qs = 0; qs < 2; ++qs) {
            const int rowl = 32 * tw + 16 * qs + lq;
            float l = ls[qs] + __shfl_xor(ls[qs], 16);
            l += __shfl_xor(l, 32);
            const float inv = 1.0f / (l + sls[rowl]);
            float* op = O + (((size_t)(b0 * L_ + qrow[qs])) * H_ + h) * D_;
            #pragma unroll
            for (int dt = 0; dt < 4; ++dt) {
                f32x4 p = *(const f32x4*)&sacc[rowl * 68 + dt * 16 + 4 * g];
                f32x4 o;
                #pragma unroll
                for (int r = 0; r < 4; ++r) o[r] = (acc[qs][dt][r] + p[r]) * inv;
                *(f32x4*)(op + dt * 16 + 4 * g) = o;
            }
        }
    }
}

// ---------------- fallback (round-1 kernel, proven) for tiny ws ----------------
#define KPITCH 72
__global__ __launch_bounds__(256, 2) void attn_fwd_fb(
    const float* __restrict__ Q, const float* __restrict__ K,
    const float* __restrict__ V, float* __restrict__ O)
{
    __shared__ unsigned short Klds[64 * KPITCH];
    __shared__ unsigned short Vlds[64 * KPITCH];
    const int tid = threadIdx.x, lane = tid & 63, w = tid >> 6;
    const int lq = lane & 15, g = lane >> 4;
    const int bid = blockIdx.x, qb = bid & 31, bh = bid >> 5;
    const int b0 = bh >> 3, h = bh & 7;
    const int q0 = qb * 64, qrow = q0 + w * 16 + lq;
    const float* qptr = Q + ((size_t)(b0 * L_ + qrow) * H_ + h) * E_;
    bf16x8 qf[2];
    #pragma unroll
    for (int eb = 0; eb < 2; ++eb) {
        const float* pp = qptr + eb * 32 + g * 8;
        f32x4 a = *(const f32x4*)pp; f32x4 b = *(const f32x4*)(pp + 4);
        bf16x8 qv;
        #pragma unroll
        for (int jq = 0; jq < 4; ++jq) { qv[jq] = (short)f2bf(a[jq] * 0.125f); qv[4 + jq] = (short)f2bf(b[jq] * 0.125f); }
        qf[eb] = qv;
    }
    const int tr = tid >> 2, tc = tid & 3;
    const int rh = rho(tr);
    f32x4 acc[4] = {};
    float mrow = -INFINITY, lrow = 0.f;
    for (int kt = 0; kt < qb + 1; ++kt) {
        const int kv0 = kt * 64;
        __syncthreads();
        {
            const float* krow = K + ((size_t)((b0 * S_ + kv0 + tr)) * H_ + h) * E_;
            const float* vrow = V + ((size_t)((b0 * S_ + kv0 + tr)) * H_ + h) * D_;
            #pragma unroll
            for (int i = 0; i < 4; ++i) {
                const int e0 = tc * 4 + i * 16;
                f32x4 k4 = *(const f32x4*)(krow + e0);
                unsigned int lo = (unsigned)f2bf(k4[0]) | ((unsigned)f2bf(k4[1]) << 16);
                unsigned int hi = (unsigned)f2bf(k4[2]) | ((unsigned)f2bf(k4[3]) << 16);
                *(uint2*)&Klds[rh * KPITCH + e0] = make_uint2(lo, hi);
                f32x4 v4 = *(const f32x4*)(vrow + e0);
                #pragma unroll
                for (int k2 = 0; k2 < 4; ++k2) Vlds[(e0 + k2) * KPITCH + tr] = f2bf(v4[k2]);
            }
        }
        __syncthreads();
        f32x4 sc[4];
        #pragma unroll
        for (int st = 0; st < 4; ++st) {
            const unsigned short* kr = &Klds[(st * 16 + lq) * KPITCH];
            bf16x8 ka0 = *(const bf16x8*)(kr + 8 * g);
            bf16x8 ka1 = *(const bf16x8*)(kr + 32 + 8 * g);
            f32x4 cc = {0.f, 0.f, 0.f, 0.f};
            cc = __builtin_amdgcn_mfma_f32_16x16x32_bf16(ka0, qf[0], cc, 0, 0, 0);
            cc = __builtin_amdgcn_mfma_f32_16x16x32_bf16(ka1, qf[1], cc, 0, 0, 0);
            sc[st] = cc;
        }
        float tmax = -INFINITY;
        #pragma unroll
        for (int st = 0; st < 4; ++st) {
            const int kvb = kv0 + 32 * (st >> 1) + 8 * g + 4 * (st & 1);
            #pragma unroll
            for (int r = 0; r < 4; ++r) { if (kvb + r > qrow) sc[st][r] = -INFINITY; tmax = fmaxf(tmax, sc[st][r]); }
        }
        tmax = fmaxf(tmax, __shfl_xor(tmax, 16));
        tmax = fmaxf(tmax, __shfl_xor(tmax, 32));
        const float mnew = fmaxf(mrow, tmax);
        const float corr = __expf(mrow - mnew);
        float pv[4][4]; float tsum = 0.f;
        #pragma unroll
        for (int st = 0; st < 4; ++st)
            #pragma unroll
            for (int r = 0; r < 4; ++r) { float e = __expf(sc[st][r] - mnew); pv[st][r] = e; tsum += e; }
        tsum += __shfl_xor(tsum, 16); tsum += __shfl_xor(tsum, 32);
        lrow = lrow * corr + tsum; mrow = mnew;
        #pragma unroll
        for (int dt = 0; dt < 4; ++dt)
            #pragma unroll
            for (int r = 0; r < 4; ++r) acc[dt][r] *= corr;
        bf16x8 pb[2];
        #pragma unroll
        for (int bb = 0; bb < 2; ++bb)
            #pragma unroll
            for (int s = 0; s < 2; ++s)
                #pragma unroll
                for (int r = 0; r < 4; ++r) pb[bb][4 * s + r] = (short)f2bf(pv[2 * bb + s][r]);
        #pragma unroll
        for (int bb = 0; bb < 2; ++bb)
            #pragma unroll
            for (int dt = 0; dt < 4; ++dt) {
                bf16x8 va = *(const bf16x8*)&Vlds[(dt * 16 + lq) * KPITCH + 32 * bb + 8 * g];
                acc[dt] = __builtin_amdgcn_mfma_f32_16x16x32_bf16(va, pb[bb], acc[dt], 0, 0, 0);
            }
    }
    const float inv = 1.0f / lrow;
    float* optr = O + ((size_t)(b0 * L_ + qrow) * H_ + h) * D_;
    #pragma unroll
    for (int dt = 0; dt < 4; ++dt) {
        f32x4 o;
        #pragma unroll
        for (int r = 0; r < 4; ++r) o[r] = acc[dt][r] * inv;
        *(f32x4*)(optr + dt * 16 + 4 * g) = o;
    }
}

extern "C" void kernel_launch(void* const* d_in, const int* in_sizes, int n_in,
                              void* d_out, int out_size, void* d_ws, size_t ws_size,
                              hipStream_t stream) {
    const float* Q = (const float*)d_in[0];
    const float* K = (const float*)d_in[1];
    const float* V = (const float*)d_in[2];
    float* O = (float*)d_out;
    if (ws_size >= WS_NEEDED) {
        prep_kv<<<dim3(B_ * H_ * NT_), 256, 0, stream>>>(K, V, (unsigned short*)d_ws);
        attn20<<<dim3(512), 512, 0, stream>>>(Q, (const unsigned short*)d_ws, O);
    } else {
        attn_fwd_fb<<<dim3(B_ * H_ * 32), 256, 0, stream>>>(Q, K, V, O);
    }
}